// Round 1
// baseline (458.926 us; speedup 1.0000x reference)
//
#include <hip/hip_runtime.h>

#define EPS 1e-5f
constexpr int B = 64, D = 512, U = 512;
constexpr float INV_N1 = 1.f / 524288.f;   // D*U*2
constexpr float INV_N3 = 1.f / 262144.f;   // D*U

__device__ __forceinline__ float lrelu(float y) { return fmaxf(y, 0.01f * y); }

__device__ __forceinline__ float waveAllSum(float v) {
    v += __shfl_xor(v, 32);
    v += __shfl_xor(v, 16);
    v += __shfl_xor(v, 8);
    v += __shfl_xor(v, 4);
    v += __shfl_xor(v, 2);
    v += __shfl_xor(v, 1);
    return v;
}

// ---------------------------------------------------------------------------
// K0a: per-d weight sums for analytic LN1 stats, plus column sums of g3/be3.
// blocks 0..511: d = bid, reduce w1/b1 over (u,k) -> S1,S0b,S2,S11,Sb2
// blocks 512..513: u-column sums of g3, be3 -> G3s, Be3s
// ---------------------------------------------------------------------------
__global__ void __launch_bounds__(256) k0a(
    const float* __restrict__ w1, const float* __restrict__ b1,
    const float* __restrict__ g3, const float* __restrict__ be3,
    float* __restrict__ S1, float* __restrict__ S0b, float* __restrict__ S2,
    float* __restrict__ S11, float* __restrict__ Sb2,
    float* __restrict__ G3s, float* __restrict__ Be3s) {
    int bid = blockIdx.x, tid = threadIdx.x;
    if (bid < 512) {
        const float4* wr = (const float4*)(w1 + bid * 1024);
        const float4* br = (const float4*)(b1 + bid * 1024);
        float4 w = wr[tid], b = br[tid];
        float s1  = w.x + w.y + w.z + w.w;
        float s2  = w.x * w.x + w.y * w.y + w.z * w.z + w.w * w.w;
        float s11 = w.x * b.x + w.y * b.y + w.z * b.z + w.w * b.w;
        float s0  = b.x + b.y + b.z + b.w;
        float sb2 = b.x * b.x + b.y * b.y + b.z * b.z + b.w * b.w;
        __shared__ float red[4][5];
        s1 = waveAllSum(s1); s2 = waveAllSum(s2); s11 = waveAllSum(s11);
        s0 = waveAllSum(s0); sb2 = waveAllSum(sb2);
        int wave = tid >> 6, lane = tid & 63;
        if (lane == 0) {
            red[wave][0] = s1; red[wave][1] = s2; red[wave][2] = s11;
            red[wave][3] = s0; red[wave][4] = sb2;
        }
        __syncthreads();
        if (tid == 0) {
            float a0 = 0, a1 = 0, a2 = 0, a3 = 0, a4 = 0;
            for (int w4 = 0; w4 < 4; ++w4) {
                a0 += red[w4][0]; a1 += red[w4][1]; a2 += red[w4][2];
                a3 += red[w4][3]; a4 += red[w4][4];
            }
            S1[bid] = a0; S2[bid] = a1; S11[bid] = a2; S0b[bid] = a3; Sb2[bid] = a4;
        }
    } else {
        int u = (bid - 512) * 256 + tid;
        float ag = 0.f, ab = 0.f;
#pragma unroll 4
        for (int d = 0; d < 512; ++d) {
            ag += g3[d * 512 + u];
            ab += be3[d * 512 + u];
        }
        G3s[u] = ag; Be3s[u] = ab;
    }
}

// ---------------------------------------------------------------------------
// K0b: per-batch LN over x (-> xn), analytic LN1 stats (rs1, m1*rs1), Xs=sum xn
// ---------------------------------------------------------------------------
__global__ void __launch_bounds__(256) k0b(
    const float* __restrict__ x, const float* __restrict__ g0, const float* __restrict__ be0,
    const float* __restrict__ S1, const float* __restrict__ S0b, const float* __restrict__ S2,
    const float* __restrict__ S11, const float* __restrict__ Sb2,
    float* __restrict__ xnp, float* __restrict__ rs1a, float* __restrict__ mm1a,
    float* __restrict__ Xs) {
    int b = blockIdx.x, tid = threadIdx.x;
    float2 xv = ((const float2*)(x + b * D))[tid];
    float sx = xv.x + xv.y;
    float sxx = xv.x * xv.x + xv.y * xv.y;
    __shared__ float red[4][3];
    __shared__ float bc[2];
    sx = waveAllSum(sx); sxx = waveAllSum(sxx);
    int wave = tid >> 6, lane = tid & 63;
    if (lane == 0) { red[wave][0] = sx; red[wave][1] = sxx; }
    __syncthreads();
    if (tid == 0) {
        float a = red[0][0] + red[1][0] + red[2][0] + red[3][0];
        float c = red[0][1] + red[1][1] + red[2][1] + red[3][1];
        float m = a * (1.f / 512.f);
        float var = c * (1.f / 512.f) - m * m;
        bc[0] = m; bc[1] = rsqrtf(var + EPS);
    }
    __syncthreads();
    float m = bc[0], rsd = bc[1];
    float2 g = ((const float2*)g0)[tid];
    float2 be = ((const float2*)be0)[tid];
    float xn0 = (xv.x - m) * rsd * g.x + be.x;
    float xn1 = (xv.y - m) * rsd * g.y + be.y;
    ((float2*)(xnp + b * D))[tid] = make_float2(xn0, xn1);
    float2 s1 = ((const float2*)S1)[tid], s0b = ((const float2*)S0b)[tid];
    float2 s2 = ((const float2*)S2)[tid], s11 = ((const float2*)S11)[tid];
    float2 sb2 = ((const float2*)Sb2)[tid];
    float pm = fmaf(xn0, s1.x, s0b.x) + fmaf(xn1, s1.y, s0b.y);
    float pe = xn0 * xn0 * s2.x + 2.f * xn0 * s11.x + sb2.x
             + xn1 * xn1 * s2.y + 2.f * xn1 * s11.y + sb2.y;
    float sxn = xn0 + xn1;
    pm = waveAllSum(pm); pe = waveAllSum(pe); sxn = waveAllSum(sxn);
    __syncthreads();
    if (lane == 0) { red[wave][0] = pm; red[wave][1] = pe; red[wave][2] = sxn; }
    __syncthreads();
    if (tid == 0) {
        float a = red[0][0] + red[1][0] + red[2][0] + red[3][0];
        float c = red[0][1] + red[1][1] + red[2][1] + red[3][1];
        float s = red[0][2] + red[1][2] + red[2][2] + red[3][2];
        float m1 = a * INV_N1;
        float e1 = c * INV_N1;
        float r = rsqrtf(e1 - m1 * m1 + EPS);
        rs1a[b] = r; mm1a[b] = m1 * r; Xs[b] = s;
    }
}

// ---------------------------------------------------------------------------
// K1: stats for LN2. Thread owns one (d,u); weights in registers; loop batches.
// Per batch: block-reduce sum(l21+l22) and sum(l21^2+l22^2) -> double atomics.
// ---------------------------------------------------------------------------
__global__ void __launch_bounds__(256) k1(
    const float* __restrict__ w1, const float* __restrict__ b1,
    const float* __restrict__ g1, const float* __restrict__ be1,
    const float* __restrict__ w21, const float* __restrict__ w22,
    const float* __restrict__ b21, const float* __restrict__ b22,
    const float* __restrict__ xnp, const float* __restrict__ rs1a,
    const float* __restrict__ mm1a, double* __restrict__ st2) {
    int bid = blockIdx.x, tid = threadIdx.x;
    int d = bid >> 1;
    int u = ((bid & 1) << 8) + tid;
    int i = d * 512 + u;
    float2 W1 = ((const float2*)w1)[i], B1 = ((const float2*)b1)[i];
    float2 G1 = ((const float2*)g1)[i], E1 = ((const float2*)be1)[i];
    float2 A = ((const float2*)w21)[i], C = ((const float2*)w22)[i];
    float Ba = b21[i], Bc = b22[i];
    __shared__ float red[4][2];
    int wave = tid >> 6, lane = tid & 63;
    for (int b = 0; b < 64; ++b) {
        float rs1 = rs1a[b], mm1 = mm1a[b];
        float xd = xnp[b * 512 + d];
        float t0 = fmaf(xd, W1.x, B1.x), t1 = fmaf(xd, W1.y, B1.y);
        float z0 = fmaf(t0, rs1, -mm1), z1 = fmaf(t1, rs1, -mm1);
        float y0 = fmaf(z0, G1.x, E1.x), y1 = fmaf(z1, G1.y, E1.y);
        float l0 = lrelu(y0), l1 = lrelu(y1);
        float c0 = fmaf(l0, A.x, fmaf(l1, A.y, Ba));
        float c1 = fmaf(l0, C.x, fmaf(l1, C.y, Bc));
        float v1 = c0 + c1;
        float v2 = fmaf(c0, c0, c1 * c1);
        v1 = waveAllSum(v1); v2 = waveAllSum(v2);
        if (lane == 0) { red[wave][0] = v1; red[wave][1] = v2; }
        __syncthreads();
        if (tid == 0) {
            float a = red[0][0] + red[1][0] + red[2][0] + red[3][0];
            float c = red[0][1] + red[1][1] + red[2][1] + red[3][1];
            atomicAdd(&st2[b * 2 + 0], (double)a);
            atomicAdd(&st2[b * 2 + 1], (double)c);
        }
        __syncthreads();
    }
}

// ---------------------------------------------------------------------------
// K2: main fused pass. 16d x 16u tile per block, weights in registers,
// loop batches; emits per-(b,u) column sums P=sum_d l3*g3, Q=sum_d l3,
// Q2=sum_d l3^2 via 2 shuffle steps + LDS combine + f32 atomics.
// ---------------------------------------------------------------------------
__global__ void __launch_bounds__(256) k2(
    const float* __restrict__ w1, const float* __restrict__ b1,
    const float* __restrict__ g1, const float* __restrict__ be1,
    const float* __restrict__ w21, const float* __restrict__ w22,
    const float* __restrict__ b21, const float* __restrict__ b22,
    const float* __restrict__ g2, const float* __restrict__ be2,
    const float* __restrict__ w3, const float* __restrict__ b3,
    const float* __restrict__ g3,
    const float* __restrict__ xnp, const float* __restrict__ rs1a,
    const float* __restrict__ mm1a, const double* __restrict__ st2,
    float* __restrict__ P, float* __restrict__ Q, float* __restrict__ Q2) {
    int bu = blockIdx.x, bd = blockIdx.y, tid = threadIdx.x;
    int ul = tid & 15, dl = tid >> 4;
    int d = bd * 16 + dl, u = bu * 16 + ul;
    int i = d * 512 + u;
    float2 W1 = ((const float2*)w1)[i], B1 = ((const float2*)b1)[i];
    float2 G1 = ((const float2*)g1)[i], E1 = ((const float2*)be1)[i];
    float2 A = ((const float2*)w21)[i], C = ((const float2*)w22)[i];
    float2 G2 = ((const float2*)g2)[i], E2 = ((const float2*)be2)[i];
    float2 W3 = ((const float2*)w3)[i];
    float Ba = b21[i], Bc = b22[i], B3 = b3[i], G3v = g3[i];
    __shared__ __align__(16) float sc[64][4];
    __shared__ float comb[4][16][3];
    if (tid < 64) {
        int b = tid;
        double s = st2[b * 2 + 0], s2 = st2[b * 2 + 1];
        double m2 = s * (1.0 / 524288.0);
        double var = s2 * (1.0 / 524288.0) - m2 * m2;
        float r2 = (float)rsqrt(var + (double)EPS);
        sc[b][0] = rs1a[b];
        sc[b][1] = mm1a[b];
        sc[b][2] = r2;
        sc[b][3] = (float)m2 * r2;
    }
    __syncthreads();
    int lane = tid & 63, wave = tid >> 6;
    for (int b = 0; b < 64; ++b) {
        float4 s4 = *(const float4*)sc[b];  // rs1, mm1, rs2, mm2
        float xd = xnp[b * 512 + d];
        // layer 1
        float t0 = fmaf(xd, W1.x, B1.x), t1 = fmaf(xd, W1.y, B1.y);
        float z0 = fmaf(t0, s4.x, -s4.y), z1 = fmaf(t1, s4.x, -s4.y);
        float y0 = fmaf(z0, G1.x, E1.x), y1 = fmaf(z1, G1.y, E1.y);
        float l0 = lrelu(y0), l1 = lrelu(y1);
        float c0 = fmaf(l0, A.x, fmaf(l1, A.y, Ba));
        float c1 = fmaf(l0, C.x, fmaf(l1, C.y, Bc));
        // layer 2
        float z20 = fmaf(c0, s4.z, -s4.w), z21 = fmaf(c1, s4.z, -s4.w);
        float y20 = fmaf(z20, G2.x, E2.x), y21 = fmaf(z21, G2.y, E2.y);
        float m0 = lrelu(y20), m1v = lrelu(y21);
        // layer 3
        float l3 = fmaf(m0, W3.x, fmaf(m1v, W3.y, B3));
        float p = l3 * G3v, q = l3, q2 = l3 * l3;
        // reduce over the wave's 4 d-rows (lanes differing in bits 4,5)
        p += __shfl_xor(p, 16);  p += __shfl_xor(p, 32);
        q += __shfl_xor(q, 16);  q += __shfl_xor(q, 32);
        q2 += __shfl_xor(q2, 16); q2 += __shfl_xor(q2, 32);
        if (lane < 16) {
            comb[wave][lane][0] = p; comb[wave][lane][1] = q; comb[wave][lane][2] = q2;
        }
        __syncthreads();
        if (tid < 48) {
            int k = tid >> 4, uu = tid & 15;
            float v = comb[0][uu][k] + comb[1][uu][k] + comb[2][uu][k] + comb[3][uu][k];
            float* dst = (k == 0) ? P : ((k == 1) ? Q : Q2);
            unsafeAtomicAdd(&dst[b * 512 + bu * 16 + uu], v);
        }
        __syncthreads();
    }
}

// ---------------------------------------------------------------------------
// K3: finalize. Per batch: LN3 stats from Q/Q2, then
// out[b,u] = lrelu(rs3*(P - m3*G3s[u]) + Be3s[u] + Xs[b] + bias[u])
// ---------------------------------------------------------------------------
__global__ void __launch_bounds__(512) k3(
    const float* __restrict__ P, const float* __restrict__ Q, const float* __restrict__ Q2,
    const float* __restrict__ G3s, const float* __restrict__ Be3s,
    const float* __restrict__ Xs, const float* __restrict__ bias,
    float* __restrict__ out) {
    int b = blockIdx.x, u = threadIdx.x;
    float q = Q[b * 512 + u], q2 = Q2[b * 512 + u];
    __shared__ float red[8][2];
    __shared__ float bc2[2];
    float sq = waveAllSum(q), sq2 = waveAllSum(q2);
    int wave = u >> 6, lane = u & 63;
    if (lane == 0) { red[wave][0] = sq; red[wave][1] = sq2; }
    __syncthreads();
    if (u == 0) {
        float a = 0, c = 0;
        for (int w = 0; w < 8; ++w) { a += red[w][0]; c += red[w][1]; }
        float m3 = a * INV_N3;
        float e3 = c * INV_N3;
        bc2[0] = m3; bc2[1] = rsqrtf(e3 - m3 * m3 + EPS);
    }
    __syncthreads();
    float m3 = bc2[0], rs3 = bc2[1];
    float val = rs3 * (P[b * 512 + u] - m3 * G3s[u]) + Be3s[u] + Xs[b] + bias[u];
    out[b * 512 + u] = lrelu(val);
}

extern "C" void kernel_launch(void* const* d_in, const int* in_sizes, int n_in,
                              void* d_out, int out_size, void* d_ws, size_t ws_size,
                              hipStream_t stream) {
    const float* x   = (const float*)d_in[0];
    const float* w1  = (const float*)d_in[1];
    const float* b1  = (const float*)d_in[2];
    const float* w21 = (const float*)d_in[3];
    const float* w22 = (const float*)d_in[4];
    const float* b21 = (const float*)d_in[5];
    const float* b22 = (const float*)d_in[6];
    const float* w3  = (const float*)d_in[7];
    const float* b3  = (const float*)d_in[8];
    const float* bias= (const float*)d_in[9];
    const float* g0  = (const float*)d_in[10];
    const float* be0 = (const float*)d_in[11];
    const float* g1  = (const float*)d_in[12];
    const float* be1 = (const float*)d_in[13];
    const float* g2  = (const float*)d_in[14];
    const float* be2 = (const float*)d_in[15];
    const float* g3  = (const float*)d_in[16];
    const float* be3 = (const float*)d_in[17];
    float* out = (float*)d_out;
    char* ws = (char*)d_ws;

    float*  xn   = (float*)(ws);             // 131072 B  [B][D]
    float*  S1   = (float*)(ws + 131072);    // 2048 B    [D]
    float*  S0b  = (float*)(ws + 133120);
    float*  S2   = (float*)(ws + 135168);
    float*  S11  = (float*)(ws + 137216);
    float*  Sb2  = (float*)(ws + 139264);
    float*  G3s  = (float*)(ws + 141312);    // [U]
    float*  Be3s = (float*)(ws + 143360);    // [U]
    float*  rs1a = (float*)(ws + 145408);    // [B]
    float*  mm1a = (float*)(ws + 145664);    // [B]
    float*  Xs   = (float*)(ws + 145920);    // [B]
    double* st2  = (double*)(ws + 146176);   // [B][2] doubles, 1024 B
    float*  P    = (float*)(ws + 147200);    // [B][U]
    float*  Q    = (float*)(ws + 278272);    // [B][U]
    float*  Q2   = (float*)(ws + 409344);    // [B][U]  (end: 540416 B)

    // zero the atomic accumulators (st2 + P + Q + Q2, contiguous)
    hipMemsetAsync(ws + 146176, 0, 540416 - 146176, stream);

    hipLaunchKernelGGL(k0a, dim3(514), dim3(256), 0, stream,
                       w1, b1, g3, be3, S1, S0b, S2, S11, Sb2, G3s, Be3s);
    hipLaunchKernelGGL(k0b, dim3(64), dim3(256), 0, stream,
                       x, g0, be0, S1, S0b, S2, S11, Sb2, xn, rs1a, mm1a, Xs);
    hipLaunchKernelGGL(k1, dim3(1024), dim3(256), 0, stream,
                       w1, b1, g1, be1, w21, w22, b21, b22, xn, rs1a, mm1a, st2);
    hipLaunchKernelGGL(k2, dim3(32, 32), dim3(256), 0, stream,
                       w1, b1, g1, be1, w21, w22, b21, b22, g2, be2, w3, b3, g3,
                       xn, rs1a, mm1a, st2, P, Q, Q2);
    hipLaunchKernelGGL(k3, dim3(64), dim3(512), 0, stream,
                       P, Q, Q2, G3s, Be3s, Xs, bias, out);
}

// Round 2
// 103.291 us; speedup vs baseline: 4.4430x; 4.4430x over previous
//
#include <hip/hip_runtime.h>

#define EPS 1e-5f
constexpr float INV_N1 = 1.f / 524288.f;   // D*U*2
constexpr float INV_N3 = 1.f / 262144.f;   // D*U

__device__ __forceinline__ float lrelu(float y) { return fmaxf(y, 0.01f * y); }

__device__ __forceinline__ float waveAllSum(float v) {
    v += __shfl_xor(v, 32);
    v += __shfl_xor(v, 16);
    v += __shfl_xor(v, 8);
    v += __shfl_xor(v, 4);
    v += __shfl_xor(v, 2);
    v += __shfl_xor(v, 1);
    return v;
}

// ---------------------------------------------------------------------------
// K0a: blocks 0..511: per-d sums of w1/b1 over (u,k) for analytic LN1 stats.
//      blocks 512..575: column sums of g3/be3 (8 d-rows per block, coalesced,
//      f32 atomic combine into zeroed G3s/Be3s).
// ---------------------------------------------------------------------------
__global__ void __launch_bounds__(256) k0a(
    const float* __restrict__ w1, const float* __restrict__ b1,
    const float* __restrict__ g3, const float* __restrict__ be3,
    float* __restrict__ S1, float* __restrict__ S0b, float* __restrict__ S2,
    float* __restrict__ S11, float* __restrict__ Sb2,
    float* __restrict__ G3s, float* __restrict__ Be3s) {
    int bid = blockIdx.x, tid = threadIdx.x;
    if (bid < 512) {
        const float4* wr = (const float4*)(w1 + bid * 1024);
        const float4* br = (const float4*)(b1 + bid * 1024);
        float4 w = wr[tid], b = br[tid];
        float s1  = w.x + w.y + w.z + w.w;
        float s2  = w.x * w.x + w.y * w.y + w.z * w.z + w.w * w.w;
        float s11 = w.x * b.x + w.y * b.y + w.z * b.z + w.w * b.w;
        float s0  = b.x + b.y + b.z + b.w;
        float sb2 = b.x * b.x + b.y * b.y + b.z * b.z + b.w * b.w;
        __shared__ float red[4][5];
        s1 = waveAllSum(s1); s2 = waveAllSum(s2); s11 = waveAllSum(s11);
        s0 = waveAllSum(s0); sb2 = waveAllSum(sb2);
        int wave = tid >> 6, lane = tid & 63;
        if (lane == 0) {
            red[wave][0] = s1; red[wave][1] = s2; red[wave][2] = s11;
            red[wave][3] = s0; red[wave][4] = sb2;
        }
        __syncthreads();
        if (tid == 0) {
            float a0 = 0, a1 = 0, a2 = 0, a3 = 0, a4 = 0;
            for (int w4 = 0; w4 < 4; ++w4) {
                a0 += red[w4][0]; a1 += red[w4][1]; a2 += red[w4][2];
                a3 += red[w4][3]; a4 += red[w4][4];
            }
            S1[bid] = a0; S2[bid] = a1; S11[bid] = a2; S0b[bid] = a3; Sb2[bid] = a4;
        }
    } else {
        int jj = bid - 512;   // 0..63, 8 d-rows each
        float ag0 = 0, ag1 = 0, ab0 = 0, ab1 = 0;
#pragma unroll
        for (int r = 0; r < 8; ++r) {
            int d = jj * 8 + r;
            const float* gr = g3 + d * 512;
            const float* br = be3 + d * 512;
            ag0 += gr[tid];       ag1 += gr[tid + 256];
            ab0 += br[tid];       ab1 += br[tid + 256];
        }
        unsafeAtomicAdd(&G3s[tid], ag0);
        unsafeAtomicAdd(&G3s[tid + 256], ag1);
        unsafeAtomicAdd(&Be3s[tid], ab0);
        unsafeAtomicAdd(&Be3s[tid + 256], ab1);
    }
}

// ---------------------------------------------------------------------------
// K0b: per-batch LN over x (-> xn), analytic LN1 stats (rs1, m1*rs1), Xs
// ---------------------------------------------------------------------------
__global__ void __launch_bounds__(256) k0b(
    const float* __restrict__ x, const float* __restrict__ g0, const float* __restrict__ be0,
    const float* __restrict__ S1, const float* __restrict__ S0b, const float* __restrict__ S2,
    const float* __restrict__ S11, const float* __restrict__ Sb2,
    float* __restrict__ xnp, float* __restrict__ rs1a, float* __restrict__ mm1a,
    float* __restrict__ Xs) {
    int b = blockIdx.x, tid = threadIdx.x;
    float2 xv = ((const float2*)(x + b * 512))[tid];
    float sx = xv.x + xv.y;
    float sxx = xv.x * xv.x + xv.y * xv.y;
    __shared__ float red[4][3];
    __shared__ float bc[2];
    sx = waveAllSum(sx); sxx = waveAllSum(sxx);
    int wave = tid >> 6, lane = tid & 63;
    if (lane == 0) { red[wave][0] = sx; red[wave][1] = sxx; }
    __syncthreads();
    if (tid == 0) {
        float a = red[0][0] + red[1][0] + red[2][0] + red[3][0];
        float c = red[0][1] + red[1][1] + red[2][1] + red[3][1];
        float m = a * (1.f / 512.f);
        float var = c * (1.f / 512.f) - m * m;
        bc[0] = m; bc[1] = rsqrtf(var + EPS);
    }
    __syncthreads();
    float m = bc[0], rsd = bc[1];
    float2 g = ((const float2*)g0)[tid];
    float2 be = ((const float2*)be0)[tid];
    float xn0 = (xv.x - m) * rsd * g.x + be.x;
    float xn1 = (xv.y - m) * rsd * g.y + be.y;
    ((float2*)(xnp + b * 512))[tid] = make_float2(xn0, xn1);
    float2 s1 = ((const float2*)S1)[tid], s0b = ((const float2*)S0b)[tid];
    float2 s2 = ((const float2*)S2)[tid], s11 = ((const float2*)S11)[tid];
    float2 sb2 = ((const float2*)Sb2)[tid];
    float pm = fmaf(xn0, s1.x, s0b.x) + fmaf(xn1, s1.y, s0b.y);
    float pe = xn0 * xn0 * s2.x + 2.f * xn0 * s11.x + sb2.x
             + xn1 * xn1 * s2.y + 2.f * xn1 * s11.y + sb2.y;
    float sxn = xn0 + xn1;
    pm = waveAllSum(pm); pe = waveAllSum(pe); sxn = waveAllSum(sxn);
    __syncthreads();
    if (lane == 0) { red[wave][0] = pm; red[wave][1] = pe; red[wave][2] = sxn; }
    __syncthreads();
    if (tid == 0) {
        float a = red[0][0] + red[1][0] + red[2][0] + red[3][0];
        float c = red[0][1] + red[1][1] + red[2][1] + red[3][1];
        float s = red[0][2] + red[1][2] + red[2][2] + red[3][2];
        float m1 = a * INV_N1;
        float e1 = c * INV_N1;
        float r = rsqrtf(e1 - m1 * m1 + EPS);
        rs1a[b] = r; mm1a[b] = m1 * r; Xs[b] = s;
    }
}

// ---------------------------------------------------------------------------
// K1: LN2 partial sums. No atomics, no in-loop barriers: each wave writes its
// per-batch sums to a private LDS slot; one barrier; one plain store per
// (batch,stat) into part1[128][1024].
// ---------------------------------------------------------------------------
__global__ void __launch_bounds__(256) k1(
    const float* __restrict__ w1, const float* __restrict__ b1,
    const float* __restrict__ g1, const float* __restrict__ be1,
    const float* __restrict__ w21, const float* __restrict__ w22,
    const float* __restrict__ b21, const float* __restrict__ b22,
    const float* __restrict__ xnp, const float* __restrict__ rs1a,
    const float* __restrict__ mm1a, float* __restrict__ part1) {
    int bid = blockIdx.x, tid = threadIdx.x;
    int d = bid >> 1;
    int u = ((bid & 1) << 8) + tid;
    int i = d * 512 + u;
    float2 W1 = ((const float2*)w1)[i], B1 = ((const float2*)b1)[i];
    float2 G1 = ((const float2*)g1)[i], E1 = ((const float2*)be1)[i];
    float2 A = ((const float2*)w21)[i], C = ((const float2*)w22)[i];
    float Ba = b21[i], Bc = b22[i];
    __shared__ float red[64][4][2];
    int wave = tid >> 6, lane = tid & 63;
    for (int b = 0; b < 64; ++b) {
        float rs1 = rs1a[b], mm1 = mm1a[b];
        float xd = xnp[b * 512 + d];
        float t0 = fmaf(xd, W1.x, B1.x), t1 = fmaf(xd, W1.y, B1.y);
        float z0 = fmaf(t0, rs1, -mm1), z1 = fmaf(t1, rs1, -mm1);
        float y0 = fmaf(z0, G1.x, E1.x), y1 = fmaf(z1, G1.y, E1.y);
        float l0 = lrelu(y0), l1 = lrelu(y1);
        float c0 = fmaf(l0, A.x, fmaf(l1, A.y, Ba));
        float c1 = fmaf(l0, C.x, fmaf(l1, C.y, Bc));
        float v1 = c0 + c1;
        float v2 = fmaf(c0, c0, c1 * c1);
        v1 = waveAllSum(v1); v2 = waveAllSum(v2);
        if (lane == 0) { red[b][wave][0] = v1; red[b][wave][1] = v2; }
    }
    __syncthreads();
    if (tid < 128) {   // tid = b*2+k
        int b = tid >> 1, k = tid & 1;
        float s = red[b][0][k] + red[b][1][k] + red[b][2][k] + red[b][3][k];
        part1[tid * 1024 + bid] = s;
    }
}

// ---------------------------------------------------------------------------
// K1b: reduce part1 rows -> LN2 stats (rs2, m2*rs2) in st2f[2*b], st2f[2*b+1]
// ---------------------------------------------------------------------------
__global__ void __launch_bounds__(256) k1b(
    const float* __restrict__ part1, float* __restrict__ st2f) {
    int b = blockIdx.x, tid = threadIdx.x;
    const float4* r1 = (const float4*)(part1 + (2 * b) * 1024);
    const float4* r2 = (const float4*)(part1 + (2 * b + 1) * 1024);
    float4 a = r1[tid], c = r2[tid];
    float s1 = a.x + a.y + a.z + a.w;
    float s2 = c.x + c.y + c.z + c.w;
    __shared__ float red[4][2];
    s1 = waveAllSum(s1); s2 = waveAllSum(s2);
    int wave = tid >> 6, lane = tid & 63;
    if (lane == 0) { red[wave][0] = s1; red[wave][1] = s2; }
    __syncthreads();
    if (tid == 0) {
        float t1 = red[0][0] + red[1][0] + red[2][0] + red[3][0];
        float t2 = red[0][1] + red[1][1] + red[2][1] + red[3][1];
        float m2 = t1 * INV_N1;
        float var = t2 * INV_N1 - m2 * m2;
        float r = rsqrtf(var + EPS);
        st2f[2 * b] = r; st2f[2 * b + 1] = m2 * r;
    }
}

// ---------------------------------------------------------------------------
// K2: main fused pass. Block = 16u x 16 d-lanes, 2 d's per thread (weights in
// registers), xn tile in LDS, double-buffered comb -> ONE barrier per batch.
// Partial mode: plain stores to part2[3][16][64][512]. Atomic fallback:
// staggered f32 atomics into PQQ[3][64][512].
// ---------------------------------------------------------------------------
struct Wt { float2 W1, B1, G1, E1, A, C, G2, E2, W3; float Ba, Bc, B3, G3v; };

template <bool ATOMIC>
__global__ void __launch_bounds__(256) k2t(
    const float* __restrict__ w1, const float* __restrict__ b1,
    const float* __restrict__ g1, const float* __restrict__ be1,
    const float* __restrict__ w21, const float* __restrict__ w22,
    const float* __restrict__ b21, const float* __restrict__ b22,
    const float* __restrict__ g2, const float* __restrict__ be2,
    const float* __restrict__ w3, const float* __restrict__ b3,
    const float* __restrict__ g3,
    const float* __restrict__ xnp, const float* __restrict__ rs1a,
    const float* __restrict__ mm1a, const float* __restrict__ st2f,
    float* __restrict__ outp) {
    int bu = blockIdx.x, bd = blockIdx.y, tid = threadIdx.x;
    int ul = tid & 15, dl = tid >> 4;
    int u = bu * 16 + ul;
    Wt wt[2];
#pragma unroll
    for (int j = 0; j < 2; ++j) {
        int d = bd * 32 + dl + 16 * j;
        int i = d * 512 + u;
        wt[j].W1 = ((const float2*)w1)[i];  wt[j].B1 = ((const float2*)b1)[i];
        wt[j].G1 = ((const float2*)g1)[i];  wt[j].E1 = ((const float2*)be1)[i];
        wt[j].A  = ((const float2*)w21)[i]; wt[j].C  = ((const float2*)w22)[i];
        wt[j].G2 = ((const float2*)g2)[i];  wt[j].E2 = ((const float2*)be2)[i];
        wt[j].W3 = ((const float2*)w3)[i];
        wt[j].Ba = b21[i]; wt[j].Bc = b22[i]; wt[j].B3 = b3[i]; wt[j].G3v = g3[i];
    }
    __shared__ float4 sc[64];
    __shared__ float sxn[64][32];
    __shared__ float comb[2][4][16][3];
    if (tid < 64)
        sc[tid] = make_float4(rs1a[tid], mm1a[tid], st2f[2 * tid], st2f[2 * tid + 1]);
    for (int idx = tid; idx < 2048; idx += 256)
        sxn[idx >> 5][idx & 31] = xnp[(idx >> 5) * 512 + bd * 32 + (idx & 31)];
    __syncthreads();
    int lane = tid & 63, wave = tid >> 6;
    int boff = (bu * 2 + bd) & 63;
    for (int bi = 0; bi < 64; ++bi) {
        int b = (bi + boff) & 63;
        float4 s4 = sc[b];   // rs1, m1*rs1, rs2, m2*rs2
        float p = 0, q = 0, q2 = 0;
#pragma unroll
        for (int j = 0; j < 2; ++j) {
            float xd = sxn[b][dl + 16 * j];
            float t0 = fmaf(xd, wt[j].W1.x, wt[j].B1.x), t1 = fmaf(xd, wt[j].W1.y, wt[j].B1.y);
            float z0 = fmaf(t0, s4.x, -s4.y), z1 = fmaf(t1, s4.x, -s4.y);
            float y0 = fmaf(z0, wt[j].G1.x, wt[j].E1.x), y1 = fmaf(z1, wt[j].G1.y, wt[j].E1.y);
            float l0 = lrelu(y0), l1 = lrelu(y1);
            float c0 = fmaf(l0, wt[j].A.x, fmaf(l1, wt[j].A.y, wt[j].Ba));
            float c1 = fmaf(l0, wt[j].C.x, fmaf(l1, wt[j].C.y, wt[j].Bc));
            float z20 = fmaf(c0, s4.z, -s4.w), z21 = fmaf(c1, s4.z, -s4.w);
            float y20 = fmaf(z20, wt[j].G2.x, wt[j].E2.x), y21 = fmaf(z21, wt[j].G2.y, wt[j].E2.y);
            float m0 = lrelu(y20), m1v = lrelu(y21);
            float l3 = fmaf(m0, wt[j].W3.x, fmaf(m1v, wt[j].W3.y, wt[j].B3));
            p = fmaf(l3, wt[j].G3v, p); q += l3; q2 = fmaf(l3, l3, q2);
        }
        // reduce over the wave's 4 d-lane groups (tid bits 4,5)
        p  += __shfl_xor(p, 16);  p  += __shfl_xor(p, 32);
        q  += __shfl_xor(q, 16);  q  += __shfl_xor(q, 32);
        q2 += __shfl_xor(q2, 16); q2 += __shfl_xor(q2, 32);
        int pb = b & 1;
        if (lane < 16) {
            comb[pb][wave][lane][0] = p; comb[pb][wave][lane][1] = q; comb[pb][wave][lane][2] = q2;
        }
        __syncthreads();
        if (tid < 48) {
            int k = tid >> 4, uu = tid & 15;
            float v = comb[pb][0][uu][k] + comb[pb][1][uu][k]
                    + comb[pb][2][uu][k] + comb[pb][3][uu][k];
            if (ATOMIC)
                unsafeAtomicAdd(&outp[(k * 64 + b) * 512 + bu * 16 + uu], v);
            else
                outp[((k * 16 + bd) * 64 + b) * 512 + bu * 16 + uu] = v;
        }
    }
}

// ---------------------------------------------------------------------------
// K3: fold bd-partials, LN3 stats over u, finalize output.
// ---------------------------------------------------------------------------
template <bool ATOMIC>
__global__ void __launch_bounds__(512) k3t(
    const float* __restrict__ part, const float* __restrict__ G3s,
    const float* __restrict__ Be3s, const float* __restrict__ Xs,
    const float* __restrict__ bias, float* __restrict__ out) {
    int b = blockIdx.x, u = threadIdx.x;
    float p = 0, q = 0, q2 = 0;
    if (ATOMIC) {
        p  = part[(0 * 64 + b) * 512 + u];
        q  = part[(1 * 64 + b) * 512 + u];
        q2 = part[(2 * 64 + b) * 512 + u];
    } else {
#pragma unroll 4
        for (int bd = 0; bd < 16; ++bd) {
            p  += part[((0 * 16 + bd) * 64 + b) * 512 + u];
            q  += part[((1 * 16 + bd) * 64 + b) * 512 + u];
            q2 += part[((2 * 16 + bd) * 64 + b) * 512 + u];
        }
    }
    __shared__ float red[8][2];
    __shared__ float bc2[2];
    float sq = waveAllSum(q), sq2 = waveAllSum(q2);
    int wave = u >> 6, lane = u & 63;
    if (lane == 0) { red[wave][0] = sq; red[wave][1] = sq2; }
    __syncthreads();
    if (u == 0) {
        float a = 0, c = 0;
        for (int w = 0; w < 8; ++w) { a += red[w][0]; c += red[w][1]; }
        float m3 = a * INV_N3;
        float e3 = c * INV_N3;
        bc2[0] = m3; bc2[1] = rsqrtf(e3 - m3 * m3 + EPS);
    }
    __syncthreads();
    float m3 = bc2[0], rs3 = bc2[1];
    float val = rs3 * (p - m3 * G3s[u]) + Be3s[u] + Xs[b] + bias[u];
    out[b * 512 + u] = lrelu(val);
}

extern "C" void kernel_launch(void* const* d_in, const int* in_sizes, int n_in,
                              void* d_out, int out_size, void* d_ws, size_t ws_size,
                              hipStream_t stream) {
    const float* x   = (const float*)d_in[0];
    const float* w1  = (const float*)d_in[1];
    const float* b1  = (const float*)d_in[2];
    const float* w21 = (const float*)d_in[3];
    const float* w22 = (const float*)d_in[4];
    const float* b21 = (const float*)d_in[5];
    const float* b22 = (const float*)d_in[6];
    const float* w3  = (const float*)d_in[7];
    const float* b3  = (const float*)d_in[8];
    const float* bias= (const float*)d_in[9];
    const float* g0  = (const float*)d_in[10];
    const float* be0 = (const float*)d_in[11];
    const float* g1  = (const float*)d_in[12];
    const float* be1 = (const float*)d_in[13];
    const float* g2  = (const float*)d_in[14];
    const float* be2 = (const float*)d_in[15];
    const float* g3  = (const float*)d_in[16];
    const float* be3 = (const float*)d_in[17];
    float* out = (float*)d_out;
    char* ws = (char*)d_ws;

    float* xn    = (float*)(ws);             // 131072   [B][D]
    float* S1    = (float*)(ws + 131072);
    float* S0b   = (float*)(ws + 133120);
    float* S2    = (float*)(ws + 135168);
    float* S11   = (float*)(ws + 137216);
    float* Sb2   = (float*)(ws + 139264);
    float* rs1a  = (float*)(ws + 141312);
    float* mm1a  = (float*)(ws + 141568);
    float* Xs    = (float*)(ws + 141824);
    float* st2f  = (float*)(ws + 142080);    // 512 B
    float* part1 = (float*)(ws + 142592);    // 524288 B [128][1024]
    float* G3s   = (float*)(ws + 666880);    // 2048
    float* Be3s  = (float*)(ws + 668928);    // 2048  (memset region starts 666880)
    float* big   = (float*)(ws + 670976);    // part2 (6291456) or PQQ (393216)

    bool usePart = ws_size >= (size_t)670976 + 6291456;
    if (usePart)
        hipMemsetAsync(ws + 666880, 0, 4096, stream);                 // G3s, Be3s
    else
        hipMemsetAsync(ws + 666880, 0, 4096 + 393216, stream);        // + PQQ

    hipLaunchKernelGGL(k0a, dim3(576), dim3(256), 0, stream,
                       w1, b1, g3, be3, S1, S0b, S2, S11, Sb2, G3s, Be3s);
    hipLaunchKernelGGL(k0b, dim3(64), dim3(256), 0, stream,
                       x, g0, be0, S1, S0b, S2, S11, Sb2, xn, rs1a, mm1a, Xs);
    hipLaunchKernelGGL(k1, dim3(1024), dim3(256), 0, stream,
                       w1, b1, g1, be1, w21, w22, b21, b22, xn, rs1a, mm1a, part1);
    hipLaunchKernelGGL(k1b, dim3(64), dim3(256), 0, stream, part1, st2f);
    if (usePart) {
        hipLaunchKernelGGL((k2t<false>), dim3(32, 16), dim3(256), 0, stream,
                           w1, b1, g1, be1, w21, w22, b21, b22, g2, be2, w3, b3, g3,
                           xn, rs1a, mm1a, st2f, big);
        hipLaunchKernelGGL((k3t<false>), dim3(64), dim3(512), 0, stream,
                           big, G3s, Be3s, Xs, bias, out);
    } else {
        hipLaunchKernelGGL((k2t<true>), dim3(32, 16), dim3(256), 0, stream,
                           w1, b1, g1, be1, w21, w22, b21, b22, g2, be2, w3, b3, g3,
                           xn, rs1a, mm1a, st2f, big);
        hipLaunchKernelGGL((k3t<true>), dim3(64), dim3(512), 0, stream,
                           big, G3s, Be3s, Xs, bias, out);
    }
}

// Round 3
// 69.796 us; speedup vs baseline: 6.5752x; 1.4799x over previous
//
#include <hip/hip_runtime.h>

#define EPS 1e-5f
constexpr float INV_N1 = 1.f / 524288.f;   // D*U*2
constexpr float INV_N3 = 1.f / 262144.f;   // D*U

__device__ __forceinline__ float lrelu(float y) { return fmaxf(y, 0.01f * y); }

__device__ __forceinline__ float waveAllSum(float v) {
    v += __shfl_xor(v, 32);
    v += __shfl_xor(v, 16);
    v += __shfl_xor(v, 8);
    v += __shfl_xor(v, 4);
    v += __shfl_xor(v, 2);
    v += __shfl_xor(v, 1);
    return v;
}

// ---- DPP reduction helpers (VALU-speed, no LDS pipe) ----------------------
template <int CTRL>
__device__ __forceinline__ float dppMove(float v) {
    return __int_as_float(__builtin_amdgcn_update_dpp(
        0, __float_as_int(v), CTRL, 0xF, 0xF, true));
}
// full 64-lane sum; result valid in lane 63
__device__ __forceinline__ float waveSumDpp(float v) {
    v += dppMove<0x111>(v);  // row_shr:1
    v += dppMove<0x112>(v);  // row_shr:2
    v += dppMove<0x114>(v);  // row_shr:4
    v += dppMove<0x118>(v);  // row_shr:8
    v += dppMove<0x142>(v);  // row_bcast:15
    v += dppMove<0x143>(v);  // row_bcast:31
    return v;
}
// sum over each 4-lane quad; all quad lanes get the sum
__device__ __forceinline__ float quadSum(float v) {
    v += dppMove<0xB1>(v);   // quad_perm [1,0,3,2]  (xor 1)
    v += dppMove<0x4E>(v);   // quad_perm [2,3,0,1]  (xor 2)
    return v;
}

// ---------------------------------------------------------------------------
// K0a: blocks 0..511: per-d sums of w1/b1 over (u,k) for analytic LN1 stats.
//      blocks 512..575: column sums of g3/be3 -> G3s, Be3s (f32 atomics).
// ---------------------------------------------------------------------------
__global__ void __launch_bounds__(256) k0a(
    const float* __restrict__ w1, const float* __restrict__ b1,
    const float* __restrict__ g3, const float* __restrict__ be3,
    float* __restrict__ S1, float* __restrict__ S0b, float* __restrict__ S2,
    float* __restrict__ S11, float* __restrict__ Sb2,
    float* __restrict__ G3s, float* __restrict__ Be3s) {
    int bid = blockIdx.x, tid = threadIdx.x;
    if (bid < 512) {
        const float4* wr = (const float4*)(w1 + bid * 1024);
        const float4* br = (const float4*)(b1 + bid * 1024);
        float4 w = wr[tid], b = br[tid];
        float s1  = w.x + w.y + w.z + w.w;
        float s2  = w.x * w.x + w.y * w.y + w.z * w.z + w.w * w.w;
        float s11 = w.x * b.x + w.y * b.y + w.z * b.z + w.w * b.w;
        float s0  = b.x + b.y + b.z + b.w;
        float sb2 = b.x * b.x + b.y * b.y + b.z * b.z + b.w * b.w;
        __shared__ float red[4][5];
        s1 = waveAllSum(s1); s2 = waveAllSum(s2); s11 = waveAllSum(s11);
        s0 = waveAllSum(s0); sb2 = waveAllSum(sb2);
        int wave = tid >> 6, lane = tid & 63;
        if (lane == 0) {
            red[wave][0] = s1; red[wave][1] = s2; red[wave][2] = s11;
            red[wave][3] = s0; red[wave][4] = sb2;
        }
        __syncthreads();
        if (tid == 0) {
            float a0 = 0, a1 = 0, a2 = 0, a3 = 0, a4 = 0;
            for (int w4 = 0; w4 < 4; ++w4) {
                a0 += red[w4][0]; a1 += red[w4][1]; a2 += red[w4][2];
                a3 += red[w4][3]; a4 += red[w4][4];
            }
            S1[bid] = a0; S2[bid] = a1; S11[bid] = a2; S0b[bid] = a3; Sb2[bid] = a4;
        }
    } else {
        int jj = bid - 512;   // 0..63, 8 d-rows each
        float ag0 = 0, ag1 = 0, ab0 = 0, ab1 = 0;
#pragma unroll
        for (int r = 0; r < 8; ++r) {
            int d = jj * 8 + r;
            const float* gr = g3 + d * 512;
            const float* br = be3 + d * 512;
            ag0 += gr[tid];       ag1 += gr[tid + 256];
            ab0 += br[tid];       ab1 += br[tid + 256];
        }
        unsafeAtomicAdd(&G3s[tid], ag0);
        unsafeAtomicAdd(&G3s[tid + 256], ag1);
        unsafeAtomicAdd(&Be3s[tid], ab0);
        unsafeAtomicAdd(&Be3s[tid + 256], ab1);
    }
}

// ---------------------------------------------------------------------------
// K0b: per-batch LN over x (-> xn), analytic LN1 stats (rs1, m1*rs1), Xs
// ---------------------------------------------------------------------------
__global__ void __launch_bounds__(256) k0b(
    const float* __restrict__ x, const float* __restrict__ g0, const float* __restrict__ be0,
    const float* __restrict__ S1, const float* __restrict__ S0b, const float* __restrict__ S2,
    const float* __restrict__ S11, const float* __restrict__ Sb2,
    float* __restrict__ xnp, float* __restrict__ rs1a, float* __restrict__ mm1a,
    float* __restrict__ Xs) {
    int b = blockIdx.x, tid = threadIdx.x;
    float2 xv = ((const float2*)(x + b * 512))[tid];
    float sx = xv.x + xv.y;
    float sxx = xv.x * xv.x + xv.y * xv.y;
    __shared__ float red[4][3];
    __shared__ float bc[2];
    sx = waveAllSum(sx); sxx = waveAllSum(sxx);
    int wave = tid >> 6, lane = tid & 63;
    if (lane == 0) { red[wave][0] = sx; red[wave][1] = sxx; }
    __syncthreads();
    if (tid == 0) {
        float a = red[0][0] + red[1][0] + red[2][0] + red[3][0];
        float c = red[0][1] + red[1][1] + red[2][1] + red[3][1];
        float m = a * (1.f / 512.f);
        float var = c * (1.f / 512.f) - m * m;
        bc[0] = m; bc[1] = rsqrtf(var + EPS);
    }
    __syncthreads();
    float m = bc[0], rsd = bc[1];
    float2 g = ((const float2*)g0)[tid];
    float2 be = ((const float2*)be0)[tid];
    float xn0 = (xv.x - m) * rsd * g.x + be.x;
    float xn1 = (xv.y - m) * rsd * g.y + be.y;
    ((float2*)(xnp + b * 512))[tid] = make_float2(xn0, xn1);
    float2 s1 = ((const float2*)S1)[tid], s0b = ((const float2*)S0b)[tid];
    float2 s2 = ((const float2*)S2)[tid], s11 = ((const float2*)S11)[tid];
    float2 sb2 = ((const float2*)Sb2)[tid];
    float pm = fmaf(xn0, s1.x, s0b.x) + fmaf(xn1, s1.y, s0b.y);
    float pe = xn0 * xn0 * s2.x + 2.f * xn0 * s11.x + sb2.x
             + xn1 * xn1 * s2.y + 2.f * xn1 * s11.y + sb2.y;
    float sxn = xn0 + xn1;
    pm = waveAllSum(pm); pe = waveAllSum(pe); sxn = waveAllSum(sxn);
    __syncthreads();
    if (lane == 0) { red[wave][0] = pm; red[wave][1] = pe; red[wave][2] = sxn; }
    __syncthreads();
    if (tid == 0) {
        float a = red[0][0] + red[1][0] + red[2][0] + red[3][0];
        float c = red[0][1] + red[1][1] + red[2][1] + red[3][1];
        float s = red[0][2] + red[1][2] + red[2][2] + red[3][2];
        float m1 = a * INV_N1;
        float e1 = c * INV_N1;
        float r = rsqrtf(e1 - m1 * m1 + EPS);
        rs1a[b] = r; mm1a[b] = m1 * r; Xs[b] = s;
    }
}

// ---------------------------------------------------------------------------
// K1: LN2 partial sums. Per batch: 2 full-wave DPP reductions (pure VALU);
// lane 63 writes per-(b,wave) slot; one barrier at end; coalesced-ish stores.
// ---------------------------------------------------------------------------
__global__ void __launch_bounds__(256) k1(
    const float* __restrict__ w1, const float* __restrict__ b1,
    const float* __restrict__ g1, const float* __restrict__ be1,
    const float* __restrict__ w21, const float* __restrict__ w22,
    const float* __restrict__ b21, const float* __restrict__ b22,
    const float* __restrict__ xnp, const float* __restrict__ rs1a,
    const float* __restrict__ mm1a, float* __restrict__ part1) {
    int bid = blockIdx.x, tid = threadIdx.x;
    int d = bid >> 1;
    int u = ((bid & 1) << 8) + tid;
    int i = d * 512 + u;
    float2 W1 = ((const float2*)w1)[i], B1 = ((const float2*)b1)[i];
    float2 G1 = ((const float2*)g1)[i], E1 = ((const float2*)be1)[i];
    float2 A = ((const float2*)w21)[i], C = ((const float2*)w22)[i];
    float Ba = b21[i], Bc = b22[i];
    __shared__ float xcol[64], scA[64], scB[64];
    __shared__ float red[64][4][2];
    if (tid < 64) {
        xcol[tid] = xnp[tid * 512 + d];
        scA[tid] = rs1a[tid];
        scB[tid] = mm1a[tid];
    }
    __syncthreads();
    int wave = tid >> 6, lane = tid & 63;
    for (int b = 0; b < 64; ++b) {
        float rs1 = scA[b], mm1 = scB[b], xd = xcol[b];
        float t0 = fmaf(xd, W1.x, B1.x), t1 = fmaf(xd, W1.y, B1.y);
        float z0 = fmaf(t0, rs1, -mm1), z1 = fmaf(t1, rs1, -mm1);
        float y0 = fmaf(z0, G1.x, E1.x), y1 = fmaf(z1, G1.y, E1.y);
        float l0 = lrelu(y0), l1 = lrelu(y1);
        float c0 = fmaf(l0, A.x, fmaf(l1, A.y, Ba));
        float c1 = fmaf(l0, C.x, fmaf(l1, C.y, Bc));
        float v1 = c0 + c1;
        float v2 = fmaf(c0, c0, c1 * c1);
        v1 = waveSumDpp(v1);
        v2 = waveSumDpp(v2);
        if (lane == 63) { red[b][wave][0] = v1; red[b][wave][1] = v2; }
    }
    __syncthreads();
    if (tid < 128) {   // tid = b*2+k
        int b = tid >> 1, k = tid & 1;
        float s = red[b][0][k] + red[b][1][k] + red[b][2][k] + red[b][3][k];
        part1[tid * 1024 + bid] = s;
    }
}

// ---------------------------------------------------------------------------
// K1b: reduce part1 rows -> LN2 stats (rs2, m2*rs2)
// ---------------------------------------------------------------------------
__global__ void __launch_bounds__(256) k1b(
    const float* __restrict__ part1, float* __restrict__ st2f) {
    int b = blockIdx.x, tid = threadIdx.x;
    const float4* r1 = (const float4*)(part1 + (2 * b) * 1024);
    const float4* r2 = (const float4*)(part1 + (2 * b + 1) * 1024);
    float4 a = r1[tid], c = r2[tid];
    float s1 = a.x + a.y + a.z + a.w;
    float s2 = c.x + c.y + c.z + c.w;
    __shared__ float red[4][2];
    s1 = waveAllSum(s1); s2 = waveAllSum(s2);
    int wave = tid >> 6, lane = tid & 63;
    if (lane == 0) { red[wave][0] = s1; red[wave][1] = s2; }
    __syncthreads();
    if (tid == 0) {
        float t1 = red[0][0] + red[1][0] + red[2][0] + red[3][0];
        float t2 = red[0][1] + red[1][1] + red[2][1] + red[3][1];
        float m2 = t1 * INV_N1;
        float var = t2 * INV_N1 - m2 * m2;
        float r = rsqrtf(var + EPS);
        st2f[2 * b] = r; st2f[2 * b + 1] = m2 * r;
    }
}

// ---------------------------------------------------------------------------
// K2: main fused pass. Lane layout: d0 = lane&3 (quad), u = (lane>>2)&15,
// d-high = wave. Quad reduce = 2 DPP adds per stat; cross-wave combine via
// per-wave LDS accumulators (no barriers in loop). q,q2 folded over u too.
// ---------------------------------------------------------------------------
struct Wt { float2 W1, B1, G1, E1, A, C, G2, E2, W3; float Ba, Bc, B3, G3v; };

template <bool PART>
__global__ void __launch_bounds__(256) k2t(
    const float* __restrict__ w1, const float* __restrict__ b1,
    const float* __restrict__ g1, const float* __restrict__ be1,
    const float* __restrict__ w21, const float* __restrict__ w22,
    const float* __restrict__ b21, const float* __restrict__ b22,
    const float* __restrict__ g2, const float* __restrict__ be2,
    const float* __restrict__ w3, const float* __restrict__ b3,
    const float* __restrict__ g3,
    const float* __restrict__ xnp, const float* __restrict__ rs1a,
    const float* __restrict__ mm1a, const float* __restrict__ st2f,
    float* __restrict__ pp, float* __restrict__ qp) {
    int bu = blockIdx.x, bd = blockIdx.y, tid = threadIdx.x;
    int lane = tid & 63, wave = tid >> 6;
    int ul = (lane >> 2) & 15, d0 = lane & 3;
    int u = bu * 16 + ul;
    int dl0 = wave * 8 + d0 * 2;        // block-local d of slot j=0
    Wt wt[2];
#pragma unroll
    for (int j = 0; j < 2; ++j) {
        int d = bd * 32 + dl0 + j;
        int i = d * 512 + u;
        wt[j].W1 = ((const float2*)w1)[i];  wt[j].B1 = ((const float2*)b1)[i];
        wt[j].G1 = ((const float2*)g1)[i];  wt[j].E1 = ((const float2*)be1)[i];
        wt[j].A  = ((const float2*)w21)[i]; wt[j].C  = ((const float2*)w22)[i];
        wt[j].G2 = ((const float2*)g2)[i];  wt[j].E2 = ((const float2*)be2)[i];
        wt[j].W3 = ((const float2*)w3)[i];
        wt[j].Ba = b21[i]; wt[j].Bc = b22[i]; wt[j].B3 = b3[i]; wt[j].G3v = g3[i];
    }
    __shared__ float4 sc[64];
    __shared__ float sxn[64][32];
    __shared__ float comb[4][64][16][3];   // [wave][b][u][stat] 48 KB
    {
        float* cz = &comb[0][0][0][0];
        for (int t = tid; t < 4 * 64 * 16 * 3; t += 256) cz[t] = 0.f;
    }
    if (tid < 64)
        sc[tid] = make_float4(rs1a[tid], mm1a[tid], st2f[2 * tid], st2f[2 * tid + 1]);
    for (int idx = tid; idx < 2048; idx += 256)
        sxn[idx >> 5][idx & 31] = xnp[(idx >> 5) * 512 + bd * 32 + (idx & 31)];
    __syncthreads();
    for (int b = 0; b < 64; ++b) {
        float4 s4 = sc[b];   // rs1, m1*rs1, rs2, m2*rs2
        float p = 0, q = 0, q2 = 0;
#pragma unroll
        for (int j = 0; j < 2; ++j) {
            float xd = sxn[b][dl0 + j];
            float t0 = fmaf(xd, wt[j].W1.x, wt[j].B1.x), t1 = fmaf(xd, wt[j].W1.y, wt[j].B1.y);
            float z0 = fmaf(t0, s4.x, -s4.y), z1 = fmaf(t1, s4.x, -s4.y);
            float y0 = fmaf(z0, wt[j].G1.x, wt[j].E1.x), y1 = fmaf(z1, wt[j].G1.y, wt[j].E1.y);
            float l0 = lrelu(y0), l1 = lrelu(y1);
            float c0 = fmaf(l0, wt[j].A.x, fmaf(l1, wt[j].A.y, wt[j].Ba));
            float c1 = fmaf(l0, wt[j].C.x, fmaf(l1, wt[j].C.y, wt[j].Bc));
            float z20 = fmaf(c0, s4.z, -s4.w), z21 = fmaf(c1, s4.z, -s4.w);
            float y20 = fmaf(z20, wt[j].G2.x, wt[j].E2.x), y21 = fmaf(z21, wt[j].G2.y, wt[j].E2.y);
            float m0 = lrelu(y20), m1v = lrelu(y21);
            float l3 = fmaf(m0, wt[j].W3.x, fmaf(m1v, wt[j].W3.y, wt[j].B3));
            p = fmaf(l3, wt[j].G3v, p); q += l3; q2 = fmaf(l3, l3, q2);
        }
        p = quadSum(p); q = quadSum(q); q2 = quadSum(q2);
        if (d0 < 3) {
            float v = (d0 == 0) ? p : ((d0 == 1) ? q : q2);
            comb[wave][b][ul][d0] += v;   // lane-private slot, no race
        }
    }
    __syncthreads();
    // fold p over waves -> per-(b,u) partial for this bd
#pragma unroll
    for (int r = 0; r < 4; ++r) {
        int idx = r * 256 + tid;
        int b = idx >> 4, uu = idx & 15;
        float s = comb[0][b][uu][0] + comb[1][b][uu][0]
                + comb[2][b][uu][0] + comb[3][b][uu][0];
        if (PART)
            pp[(bd * 64 + b) * 512 + bu * 16 + uu] = s;
        else
            unsafeAtomicAdd(&pp[b * 512 + bu * 16 + uu], s);
    }
    // fold q,q2 over waves AND u -> per-(block,b) scalars (plain stores)
    if (tid < 128) {
        int b = tid >> 1, st = 1 + (tid & 1);
        float s = 0;
#pragma unroll
        for (int w = 0; w < 4; ++w)
#pragma unroll
            for (int uu = 0; uu < 16; ++uu) s += comb[w][b][uu][st];
        qp[(bd * 32 + bu) * 128 + b * 2 + (st - 1)] = s;
    }
}

// ---------------------------------------------------------------------------
// K3: LN3 stats from q-partials (512 columns), fold p-partials, finalize.
// ---------------------------------------------------------------------------
template <bool PART>
__global__ void __launch_bounds__(512) k3t(
    const float* __restrict__ pp, const float* __restrict__ qp,
    const float* __restrict__ G3s, const float* __restrict__ Be3s,
    const float* __restrict__ Xs, const float* __restrict__ bias,
    float* __restrict__ out) {
    int b = blockIdx.x, u = threadIdx.x;
    float q  = qp[u * 128 + b * 2 + 0];
    float q2 = qp[u * 128 + b * 2 + 1];
    __shared__ float red[8][2];
    __shared__ float bc2[2];
    float sq = waveAllSum(q), sq2 = waveAllSum(q2);
    int wave = u >> 6, lane = u & 63;
    if (lane == 0) { red[wave][0] = sq; red[wave][1] = sq2; }
    __syncthreads();
    if (u == 0) {
        float a = 0, c = 0;
        for (int w = 0; w < 8; ++w) { a += red[w][0]; c += red[w][1]; }
        float m3 = a * INV_N3;
        float e3 = c * INV_N3;
        bc2[0] = m3; bc2[1] = rsqrtf(e3 - m3 * m3 + EPS);
    }
    __syncthreads();
    float p = 0;
    if (PART) {
#pragma unroll 4
        for (int bd = 0; bd < 16; ++bd) p += pp[(bd * 64 + b) * 512 + u];
    } else {
        p = pp[b * 512 + u];
    }
    float m3 = bc2[0], rs3 = bc2[1];
    float val = rs3 * (p - m3 * G3s[u]) + Be3s[u] + Xs[b] + bias[u];
    out[b * 512 + u] = lrelu(val);
}

extern "C" void kernel_launch(void* const* d_in, const int* in_sizes, int n_in,
                              void* d_out, int out_size, void* d_ws, size_t ws_size,
                              hipStream_t stream) {
    const float* x   = (const float*)d_in[0];
    const float* w1  = (const float*)d_in[1];
    const float* b1  = (const float*)d_in[2];
    const float* w21 = (const float*)d_in[3];
    const float* w22 = (const float*)d_in[4];
    const float* b21 = (const float*)d_in[5];
    const float* b22 = (const float*)d_in[6];
    const float* w3  = (const float*)d_in[7];
    const float* b3  = (const float*)d_in[8];
    const float* bias= (const float*)d_in[9];
    const float* g0  = (const float*)d_in[10];
    const float* be0 = (const float*)d_in[11];
    const float* g1  = (const float*)d_in[12];
    const float* be1 = (const float*)d_in[13];
    const float* g2  = (const float*)d_in[14];
    const float* be2 = (const float*)d_in[15];
    const float* g3  = (const float*)d_in[16];
    const float* be3 = (const float*)d_in[17];
    float* out = (float*)d_out;
    char* ws = (char*)d_ws;

    float* xn    = (float*)(ws);             // 131072   [B][D]
    float* S1    = (float*)(ws + 131072);
    float* S0b   = (float*)(ws + 133120);
    float* S2    = (float*)(ws + 135168);
    float* S11   = (float*)(ws + 137216);
    float* Sb2   = (float*)(ws + 139264);
    float* rs1a  = (float*)(ws + 141312);
    float* mm1a  = (float*)(ws + 141568);
    float* Xs    = (float*)(ws + 141824);
    float* st2f  = (float*)(ws + 142080);    // 512 B
    float* part1 = (float*)(ws + 142592);    // 524288 B [128][1024]
    float* G3s   = (float*)(ws + 666880);    // 2048
    float* Be3s  = (float*)(ws + 668928);    // 2048
    float* qp    = (float*)(ws + 670976);    // 262144 B [512][64][2]
    float* pp    = (float*)(ws + 933120);    // PART: [16][64][512] 2 MB, else [64][512] 128 KB

    bool part = ws_size >= (size_t)933120 + 2097152;
    hipMemsetAsync(ws + 666880, 0, 4096, stream);           // G3s, Be3s
    if (!part)
        hipMemsetAsync(ws + 933120, 0, 131072, stream);     // atomic p-accumulator

    hipLaunchKernelGGL(k0a, dim3(576), dim3(256), 0, stream,
                       w1, b1, g3, be3, S1, S0b, S2, S11, Sb2, G3s, Be3s);
    hipLaunchKernelGGL(k0b, dim3(64), dim3(256), 0, stream,
                       x, g0, be0, S1, S0b, S2, S11, Sb2, xn, rs1a, mm1a, Xs);
    hipLaunchKernelGGL(k1, dim3(1024), dim3(256), 0, stream,
                       w1, b1, g1, be1, w21, w22, b21, b22, xn, rs1a, mm1a, part1);
    hipLaunchKernelGGL(k1b, dim3(64), dim3(256), 0, stream, part1, st2f);
    if (part) {
        hipLaunchKernelGGL((k2t<true>), dim3(32, 16), dim3(256), 0, stream,
                           w1, b1, g1, be1, w21, w22, b21, b22, g2, be2, w3, b3, g3,
                           xn, rs1a, mm1a, st2f, pp, qp);
        hipLaunchKernelGGL((k3t<true>), dim3(64), dim3(512), 0, stream,
                           pp, qp, G3s, Be3s, Xs, bias, out);
    } else {
        hipLaunchKernelGGL((k2t<false>), dim3(32, 16), dim3(256), 0, stream,
                           w1, b1, g1, be1, w21, w22, b21, b22, g2, be2, w3, b3, g3,
                           xn, rs1a, mm1a, st2f, pp, qp);
        hipLaunchKernelGGL((k3t<false>), dim3(64), dim3(512), 0, stream,
                           pp, qp, G3s, Be3s, Xs, bias, out);
    }
}